// Round 8
// baseline (3009.497 us; speedup 1.0000x reference)
//
#include <hip/hip_runtime.h>
#include <hip/hip_bf16.h>

#define MDIM 4096
#define DDIM 2048
#define HDIM 2048
#define EDIM 8
#define HD   ((size_t)HDIM * DDIM)

typedef float v4f __attribute__((ext_vector_type(4)));
typedef int   v4i __attribute__((ext_vector_type(4)));
typedef int   v8i __attribute__((ext_vector_type(8)));

// ---------------- Kernel 1: gating softmax + fp8 quantize of x ----------------
__global__ __launch_bounds__(256) void k_gate_xq(
    const float* __restrict__ x, const float* __restrict__ gw,
    const float* __restrict__ gb, float* __restrict__ gate,
    unsigned char* __restrict__ x8)
{
  const int wid  = threadIdx.x >> 6;
  const int lane = threadIdx.x & 63;
  const int m    = blockIdx.x * 4 + wid;

  const float4* xr = (const float4*)(x + (size_t)m * DDIM);
  unsigned int* qr = (unsigned int*)(x8 + (size_t)m * DDIM);

  float part[EDIM];
#pragma unroll
  for (int e = 0; e < EDIM; ++e) part[e] = 0.f;

#pragma unroll
  for (int it = 0; it < DDIM / 4 / 64; ++it) {   // 8 iterations
    const int idx = it * 64 + lane;
    const float4 xv = xr[idx];
    int pk = __builtin_amdgcn_cvt_pk_fp8_f32(xv.x, xv.y, 0, false);
    pk = __builtin_amdgcn_cvt_pk_fp8_f32(xv.z, xv.w, pk, true);
    qr[idx] = (unsigned int)pk;
#pragma unroll
    for (int e = 0; e < EDIM; ++e) {
      const float4 wv = ((const float4*)(gw + (size_t)e * DDIM))[idx];
      part[e] += xv.x * wv.x + xv.y * wv.y + xv.z * wv.z + xv.w * wv.w;
    }
  }
#pragma unroll
  for (int e = 0; e < EDIM; ++e) {
#pragma unroll
    for (int off = 32; off > 0; off >>= 1)
      part[e] += __shfl_xor(part[e], off);
  }
  float lg[EDIM];
  float s = 0.f;
#pragma unroll
  for (int e = 0; e < EDIM; ++e) lg[e] = part[e] + gb[e];
  float mx = lg[0];
#pragma unroll
  for (int e = 1; e < EDIM; ++e) mx = fmaxf(mx, lg[e]);
#pragma unroll
  for (int e = 0; e < EDIM; ++e) { lg[e] = expf(lg[e] - mx); s += lg[e]; }
  const float inv = 1.f / s;
  if (lane < EDIM) gate[m * EDIM + lane] = lg[lane] * inv;
}

// ---------------- Kernel 2: fp8 quantize of expert_w --------------------------
__global__ void k_wq(const float* __restrict__ w, unsigned char* __restrict__ w8)
{
  const long long n4 = (long long)EDIM * HDIM * DDIM / 4;
  const long long stride = (long long)gridDim.x * blockDim.x;
  for (long long i = (long long)blockIdx.x * blockDim.x + threadIdx.x; i < n4;
       i += stride) {
    const float4 v = ((const float4*)w)[i];
    int pk = __builtin_amdgcn_cvt_pk_fp8_f32(v.x, v.y, 0, false);
    pk = __builtin_amdgcn_cvt_pk_fp8_f32(v.z, v.w, pk, true);
    ((unsigned int*)w8)[i] = (unsigned int)pk;
  }
}

// ---------------- Kernel 3: fused grouped GEMM + gated combine ----------------
// ALL-REGISTER GEMM: no LDS staging of A/B, no barriers, no vmcnt asm, no
// swizzle. 512 threads (8 waves, 4m x 2n), tile 256x128, per-wave 64x64.
// Each wave loads its MFMA fragments directly global->VGPR (dwordx4 pairs;
// 4 lanes of a row-group share one 128B line; A slice L1-resident, B slices
// L2-resident under XCD chunking). kt-outer / expert-inner: av[4] loaded once
// per k-tile, reused for all 8 experts (8x A-reuse in registers); per-k-tile
// gate-FMA outacc += g_e * mfma(A, B_e, 0) -- algebra validated in R5/R6
// (absmax 0.015625). Single scheduling region => LLVM can remat/sink freely
// (R7's barrier-fenced regions caused 8.4GB of scratch spill).
// Only LDS: 8KB gate broadcast cache + one __syncthreads.
__global__ __launch_bounds__(512, 2) void k_moe_gemm(
    const unsigned char* __restrict__ x8,   // [M, D]
    const unsigned char* __restrict__ w8,   // [E, H, D]
    const float* __restrict__ gate,         // [M, 8]
    float* __restrict__ out)                // [M, H] f32
{
  __shared__ float sGf[EDIM * 256];         // [e][m-row] gate cache, 8 KB

  const int tid  = threadIdx.x;
  const int lane = tid & 63;
  const int wid  = tid >> 6;
  const int wm   = wid >> 1;        // 0..3  (64-row group)
  const int wn   = wid & 1;         // 0..1  (64-col group)

  // XCD chunking: 256 blocks; each XCD owns a 4x8 square of (m,h) tiles.
  const int bid   = blockIdx.x;
  const int xcd   = bid & 7;
  const int local = bid >> 3;                        // 0..31
  const int tm    = (xcd >> 1) * 4 + (local >> 3);   // 0..15
  const int tn    = (xcd & 1) * 8 + (local & 7);     // 0..15
  const int bm    = tm * 256;
  const int bn    = tn * 128;

  const int lrow = lane & 15;
  const int lk   = lane >> 4;       // 0..3 -> k-block of 32 bytes

  // fragment base pointers (per lane)
  const unsigned char* aptr =
      x8 + (size_t)(bm + wm * 64 + lrow) * DDIM + lk * 32;
  const unsigned char* bptr =
      w8 + (size_t)(bn + wn * 64 + lrow) * DDIM + lk * 32;

  // gate cache fill: thread tid covers expert tid>>6, rows 4*(tid&63)..+3
  {
    const int e = tid >> 6, grp = tid & 63;
    float4 gv;
    gv.x = gate[(size_t)(bm + 4 * grp + 0) * EDIM + e];
    gv.y = gate[(size_t)(bm + 4 * grp + 1) * EDIM + e];
    gv.z = gate[(size_t)(bm + 4 * grp + 2) * EDIM + e];
    gv.w = gate[(size_t)(bm + 4 * grp + 3) * EDIM + e];
    *(float4*)(sGf + e * 256 + 4 * grp) = gv;
  }
  __syncthreads();

  v4f outacc[4][4];
#pragma unroll
  for (int i = 0; i < 4; ++i)
#pragma unroll
    for (int j = 0; j < 4; ++j) {
      outacc[i][j][0] = 0.f; outacc[i][j][1] = 0.f;
      outacc[i][j][2] = 0.f; outacc[i][j][3] = 0.f;
    }
  const v4f zero4 = {0.f, 0.f, 0.f, 0.f};

  for (int kt = 0; kt < 16; ++kt) {
    const size_t ko = (size_t)kt * 128;

    // A fragments for this k-tile: loaded once, reused for all 8 experts
    v8i av[4];
#pragma unroll
    for (int f = 0; f < 4; ++f) {
      const unsigned char* pa = aptr + (size_t)f * (16 * DDIM) + ko;
      union { v8i v; v4i h[2]; } u;
      u.h[0] = *(const v4i*)(pa);
      u.h[1] = *(const v4i*)(pa + 16);
      av[f] = u.v;
    }

#pragma unroll
    for (int e = 0; e < EDIM; ++e) {
      // gates for this expert (broadcast reads from LDS)
      v4f g4[4];
#pragma unroll
      for (int i = 0; i < 4; ++i)
        g4[i] = *(const v4f*)(sGf + e * 256 + wm * 64 + i * 16 + lk * 4);

      const unsigned char* pbase = bptr + (size_t)e * HD + ko;
#pragma unroll
      for (int j = 0; j < 4; ++j) {
        const unsigned char* pb = pbase + (size_t)j * (16 * DDIM);
        union { v8i v; v4i h[2]; } u;
        u.h[0] = *(const v4i*)(pb);
        u.h[1] = *(const v4i*)(pb + 16);
        const v8i bv = u.v;
#pragma unroll
        for (int i = 0; i < 4; ++i) {
          const v4f t = __builtin_amdgcn_mfma_scale_f32_16x16x128_f8f6f4(
              av[i], bv, zero4, 0 /*fp8*/, 0 /*fp8*/,
              0, 127 /*e8m0 1.0*/, 0, 127 /*e8m0 1.0*/);
          outacc[i][j][0] += g4[i][0] * t[0];
          outacc[i][j][1] += g4[i][1] * t[1];
          outacc[i][j][2] += g4[i][2] * t[2];
          outacc[i][j][3] += g4[i][3] * t[3];
        }
      }
    }
  }

  // epilogue: direct coalesced stores (single block per output tile)
#pragma unroll
  for (int i = 0; i < 4; ++i)
#pragma unroll
    for (int q = 0; q < 4; ++q) {
      const size_t r = (size_t)(bm + wm * 64 + i * 16 + lk * 4 + q);
      float* orow = out + r * HDIM + bn + wn * 64 + lrow;
#pragma unroll
      for (int j = 0; j < 4; ++j)
        orow[j * 16] = outacc[i][j][q];
    }
}

extern "C" void kernel_launch(void* const* d_in, const int* in_sizes, int n_in,
                              void* d_out, int out_size, void* d_ws, size_t ws_size,
                              hipStream_t stream) {
  (void)in_sizes; (void)n_in; (void)out_size; (void)ws_size;
  const float* x        = (const float*)d_in[0];
  const float* gate_w   = (const float*)d_in[1];
  const float* gate_b   = (const float*)d_in[2];
  const float* expert_w = (const float*)d_in[3];
  float* out = (float*)d_out;

  char* ws = (char*)d_ws;
  float* gate       = (float*)ws;                                   // 131072 B
  unsigned char* x8 = (unsigned char*)(ws + 131072);                // 8 MiB
  unsigned char* w8 = (unsigned char*)(ws + 131072 + (size_t)MDIM * DDIM);

  hipLaunchKernelGGL(k_gate_xq, dim3(MDIM / 4), dim3(256), 0, stream,
                     x, gate_w, gate_b, gate, x8);
  hipLaunchKernelGGL(k_wq, dim3(4096), dim3(256), 0, stream, expert_w, w8);
  hipLaunchKernelGGL(k_moe_gemm, dim3(256), dim3(512), 0, stream,
                     x8, w8, gate, out);
}

// Round 9
// 3008.077 us; speedup vs baseline: 1.0005x; 1.0005x over previous
//
#include <hip/hip_runtime.h>
#include <hip/hip_bf16.h>

#define MDIM 4096
#define DDIM 2048
#define HDIM 2048
#define EDIM 8
#define HD   ((size_t)HDIM * DDIM)

typedef float v4f __attribute__((ext_vector_type(4)));
typedef int   v4i __attribute__((ext_vector_type(4)));
typedef int   v8i __attribute__((ext_vector_type(8)));

// ---------------- Kernel 1: gating softmax + fp8 quantize of x ----------------
__global__ __launch_bounds__(256) void k_gate_xq(
    const float* __restrict__ x, const float* __restrict__ gw,
    const float* __restrict__ gb, float* __restrict__ gate,
    unsigned char* __restrict__ x8)
{
  const int wid  = threadIdx.x >> 6;
  const int lane = threadIdx.x & 63;
  const int m    = blockIdx.x * 4 + wid;

  const float4* xr = (const float4*)(x + (size_t)m * DDIM);
  unsigned int* qr = (unsigned int*)(x8 + (size_t)m * DDIM);

  float part[EDIM];
#pragma unroll
  for (int e = 0; e < EDIM; ++e) part[e] = 0.f;

#pragma unroll
  for (int it = 0; it < DDIM / 4 / 64; ++it) {   // 8 iterations
    const int idx = it * 64 + lane;
    const float4 xv = xr[idx];
    int pk = __builtin_amdgcn_cvt_pk_fp8_f32(xv.x, xv.y, 0, false);
    pk = __builtin_amdgcn_cvt_pk_fp8_f32(xv.z, xv.w, pk, true);
    qr[idx] = (unsigned int)pk;
#pragma unroll
    for (int e = 0; e < EDIM; ++e) {
      const float4 wv = ((const float4*)(gw + (size_t)e * DDIM))[idx];
      part[e] += xv.x * wv.x + xv.y * wv.y + xv.z * wv.z + xv.w * wv.w;
    }
  }
#pragma unroll
  for (int e = 0; e < EDIM; ++e) {
#pragma unroll
    for (int off = 32; off > 0; off >>= 1)
      part[e] += __shfl_xor(part[e], off);
  }
  float lg[EDIM];
  float s = 0.f;
#pragma unroll
  for (int e = 0; e < EDIM; ++e) lg[e] = part[e] + gb[e];
  float mx = lg[0];
#pragma unroll
  for (int e = 1; e < EDIM; ++e) mx = fmaxf(mx, lg[e]);
#pragma unroll
  for (int e = 0; e < EDIM; ++e) { lg[e] = expf(lg[e] - mx); s += lg[e]; }
  const float inv = 1.f / s;
  if (lane < EDIM) gate[m * EDIM + lane] = lg[lane] * inv;
}

// ---------------- Kernel 2: fp8 quantize of expert_w --------------------------
__global__ void k_wq(const float* __restrict__ w, unsigned char* __restrict__ w8)
{
  const long long n4 = (long long)EDIM * HDIM * DDIM / 4;
  const long long stride = (long long)gridDim.x * blockDim.x;
  for (long long i = (long long)blockIdx.x * blockDim.x + threadIdx.x; i < n4;
       i += stride) {
    const float4 v = ((const float4*)w)[i];
    int pk = __builtin_amdgcn_cvt_pk_fp8_f32(v.x, v.y, 0, false);
    pk = __builtin_amdgcn_cvt_pk_fp8_f32(v.z, v.w, pk, true);
    ((unsigned int*)w8)[i] = (unsigned int)pk;
  }
}

// ---------------- Kernel 3: fused grouped GEMM + gated combine ----------------
// ALL-REGISTER GEMM: no LDS staging of A/B, no barriers, no vmcnt asm, no
// swizzle. 512 threads (8 waves, 4m x 2n), tile 256x128, per-wave 64x64.
// Fragments loaded directly global->VGPR; kt-outer / expert-inner; av[4]
// reused across all 8 experts via per-k-tile gate-FMA (validated R5/R6).
//
// CRITICAL FIX vs R6/R7/R8: __launch_bounds__(512, 2) capped the allocator
// at 128 VGPRs (2nd arg acts as min BLOCKS/CU here: 2 blk x 8 waves = 16
// waves/CU = 4 waves/SIMD -> 2048/4/4 = 128) -> every >128-reg design
// spilled GBs to scratch (R6: 2.9GB, R7: 8.4GB, R8: 9.4GB; VGPR_Count
// printed exactly 128 each time). (512, 1) -> 8 waves/CU -> 2 waves/SIMD
// -> 256-reg cap; this kernel needs ~200.
__global__ __launch_bounds__(512, 1) void k_moe_gemm(
    const unsigned char* __restrict__ x8,   // [M, D]
    const unsigned char* __restrict__ w8,   // [E, H, D]
    const float* __restrict__ gate,         // [M, 8]
    float* __restrict__ out)                // [M, H] f32
{
  __shared__ float sGf[EDIM * 256];         // [e][m-row] gate cache, 8 KB

  const int tid  = threadIdx.x;
  const int lane = tid & 63;
  const int wid  = tid >> 6;
  const int wm   = wid >> 1;        // 0..3  (64-row group)
  const int wn   = wid & 1;         // 0..1  (64-col group)

  // XCD chunking: 256 blocks; each XCD owns a 4x8 square of (m,h) tiles.
  const int bid   = blockIdx.x;
  const int xcd   = bid & 7;
  const int local = bid >> 3;                        // 0..31
  const int tm    = (xcd >> 1) * 4 + (local >> 3);   // 0..15
  const int tn    = (xcd & 1) * 8 + (local & 7);     // 0..15
  const int bm    = tm * 256;
  const int bn    = tn * 128;

  const int lrow = lane & 15;
  const int lk   = lane >> 4;       // 0..3 -> k-block of 32 bytes

  // fragment base pointers (per lane)
  const unsigned char* aptr =
      x8 + (size_t)(bm + wm * 64 + lrow) * DDIM + lk * 32;
  const unsigned char* bptr =
      w8 + (size_t)(bn + wn * 64 + lrow) * DDIM + lk * 32;

  // gate cache fill: thread tid covers expert tid>>6, rows 4*(tid&63)..+3
  {
    const int e = tid >> 6, grp = tid & 63;
    float4 gv;
    gv.x = gate[(size_t)(bm + 4 * grp + 0) * EDIM + e];
    gv.y = gate[(size_t)(bm + 4 * grp + 1) * EDIM + e];
    gv.z = gate[(size_t)(bm + 4 * grp + 2) * EDIM + e];
    gv.w = gate[(size_t)(bm + 4 * grp + 3) * EDIM + e];
    *(float4*)(sGf + e * 256 + 4 * grp) = gv;
  }
  __syncthreads();

  v4f outacc[4][4];
#pragma unroll
  for (int i = 0; i < 4; ++i)
#pragma unroll
    for (int j = 0; j < 4; ++j) {
      outacc[i][j][0] = 0.f; outacc[i][j][1] = 0.f;
      outacc[i][j][2] = 0.f; outacc[i][j][3] = 0.f;
    }
  const v4f zero4 = {0.f, 0.f, 0.f, 0.f};

  for (int kt = 0; kt < 16; ++kt) {
    const size_t ko = (size_t)kt * 128;

    // A fragments for this k-tile: loaded once, reused for all 8 experts
    v8i av[4];
#pragma unroll
    for (int f = 0; f < 4; ++f) {
      const unsigned char* pa = aptr + (size_t)f * (16 * DDIM) + ko;
      union { v8i v; v4i h[2]; } u;
      u.h[0] = *(const v4i*)(pa);
      u.h[1] = *(const v4i*)(pa + 16);
      av[f] = u.v;
    }

#pragma unroll
    for (int e = 0; e < EDIM; ++e) {
      // gates for this expert (broadcast reads from LDS)
      v4f g4[4];
#pragma unroll
      for (int i = 0; i < 4; ++i)
        g4[i] = *(const v4f*)(sGf + e * 256 + wm * 64 + i * 16 + lk * 4);

      const unsigned char* pbase = bptr + (size_t)e * HD + ko;
#pragma unroll
      for (int j = 0; j < 4; ++j) {
        const unsigned char* pb = pbase + (size_t)j * (16 * DDIM);
        union { v8i v; v4i h[2]; } u;
        u.h[0] = *(const v4i*)(pb);
        u.h[1] = *(const v4i*)(pb + 16);
        const v8i bv = u.v;
#pragma unroll
        for (int i = 0; i < 4; ++i) {
          const v4f t = __builtin_amdgcn_mfma_scale_f32_16x16x128_f8f6f4(
              av[i], bv, zero4, 0 /*fp8*/, 0 /*fp8*/,
              0, 127 /*e8m0 1.0*/, 0, 127 /*e8m0 1.0*/);
          outacc[i][j][0] += g4[i][0] * t[0];
          outacc[i][j][1] += g4[i][1] * t[1];
          outacc[i][j][2] += g4[i][2] * t[2];
          outacc[i][j][3] += g4[i][3] * t[3];
        }
      }
    }
  }

  // epilogue: direct coalesced stores (single block per output tile)
#pragma unroll
  for (int i = 0; i < 4; ++i)
#pragma unroll
    for (int q = 0; q < 4; ++q) {
      const size_t r = (size_t)(bm + wm * 64 + i * 16 + lk * 4 + q);
      float* orow = out + r * HDIM + bn + wn * 64 + lrow;
#pragma unroll
      for (int j = 0; j < 4; ++j)
        orow[j * 16] = outacc[i][j][q];
    }
}

extern "C" void kernel_launch(void* const* d_in, const int* in_sizes, int n_in,
                              void* d_out, int out_size, void* d_ws, size_t ws_size,
                              hipStream_t stream) {
  (void)in_sizes; (void)n_in; (void)out_size; (void)ws_size;
  const float* x        = (const float*)d_in[0];
  const float* gate_w   = (const float*)d_in[1];
  const float* gate_b   = (const float*)d_in[2];
  const float* expert_w = (const float*)d_in[3];
  float* out = (float*)d_out;

  char* ws = (char*)d_ws;
  float* gate       = (float*)ws;                                   // 131072 B
  unsigned char* x8 = (unsigned char*)(ws + 131072);                // 8 MiB
  unsigned char* w8 = (unsigned char*)(ws + 131072 + (size_t)MDIM * DDIM);

  hipLaunchKernelGGL(k_gate_xq, dim3(MDIM / 4), dim3(256), 0, stream,
                     x, gate_w, gate_b, gate, x8);
  hipLaunchKernelGGL(k_wq, dim3(4096), dim3(256), 0, stream, expert_w, w8);
  hipLaunchKernelGGL(k_moe_gemm, dim3(256), dim3(512), 0, stream,
                     x8, w8, gate, out);
}

// Round 10
// 209.865 us; speedup vs baseline: 14.3401x; 14.3334x over previous
//
#include <hip/hip_runtime.h>
#include <hip/hip_bf16.h>

#define MDIM 4096
#define DDIM 2048
#define HDIM 2048
#define EDIM 8
#define HD   ((size_t)HDIM * DDIM)

typedef float v4f __attribute__((ext_vector_type(4)));
typedef int   v4i __attribute__((ext_vector_type(4)));
typedef int   v8i __attribute__((ext_vector_type(8)));

// async global->LDS, 16B per lane. lds pointer must be wave-uniform
// (HW writes base + lane*16).
__device__ __forceinline__ void gl2lds16(const void* g, void* l) {
  __builtin_amdgcn_global_load_lds(
      (const __attribute__((address_space(1))) void*)g,
      (__attribute__((address_space(3))) void*)l,
      16, 0, 0);
}

// ---------------- Kernel 1: gating softmax + fp8 quantize of x ----------------
__global__ __launch_bounds__(256) void k_gate_xq(
    const float* __restrict__ x, const float* __restrict__ gw,
    const float* __restrict__ gb, float* __restrict__ gate,
    unsigned char* __restrict__ x8)
{
  const int wid  = threadIdx.x >> 6;
  const int lane = threadIdx.x & 63;
  const int m    = blockIdx.x * 4 + wid;

  const float4* xr = (const float4*)(x + (size_t)m * DDIM);
  unsigned int* qr = (unsigned int*)(x8 + (size_t)m * DDIM);

  float part[EDIM];
#pragma unroll
  for (int e = 0; e < EDIM; ++e) part[e] = 0.f;

#pragma unroll
  for (int it = 0; it < DDIM / 4 / 64; ++it) {   // 8 iterations
    const int idx = it * 64 + lane;
    const float4 xv = xr[idx];
    int pk = __builtin_amdgcn_cvt_pk_fp8_f32(xv.x, xv.y, 0, false);
    pk = __builtin_amdgcn_cvt_pk_fp8_f32(xv.z, xv.w, pk, true);
    qr[idx] = (unsigned int)pk;
#pragma unroll
    for (int e = 0; e < EDIM; ++e) {
      const float4 wv = ((const float4*)(gw + (size_t)e * DDIM))[idx];
      part[e] += xv.x * wv.x + xv.y * wv.y + xv.z * wv.z + xv.w * wv.w;
    }
  }
#pragma unroll
  for (int e = 0; e < EDIM; ++e) {
#pragma unroll
    for (int off = 32; off > 0; off >>= 1)
      part[e] += __shfl_xor(part[e], off);
  }
  float lg[EDIM];
  float s = 0.f;
#pragma unroll
  for (int e = 0; e < EDIM; ++e) lg[e] = part[e] + gb[e];
  float mx = lg[0];
#pragma unroll
  for (int e = 1; e < EDIM; ++e) mx = fmaxf(mx, lg[e]);
#pragma unroll
  for (int e = 0; e < EDIM; ++e) { lg[e] = expf(lg[e] - mx); s += lg[e]; }
  const float inv = 1.f / s;
  if (lane < EDIM) gate[m * EDIM + lane] = lg[lane] * inv;
}

// ---------------- Kernel 2: fp8 quantize of expert_w --------------------------
__global__ void k_wq(const float* __restrict__ w, unsigned char* __restrict__ w8)
{
  const long long n4 = (long long)EDIM * HDIM * DDIM / 4;
  const long long stride = (long long)gridDim.x * blockDim.x;
  for (long long i = (long long)blockIdx.x * blockDim.x + threadIdx.x; i < n4;
       i += stride) {
    const float4 v = ((const float4*)w)[i];
    int pk = __builtin_amdgcn_cvt_pk_fp8_f32(v.x, v.y, 0, false);
    pk = __builtin_amdgcn_cvt_pk_fp8_f32(v.z, v.w, pk, true);
    ((unsigned int*)w8)[i] = (unsigned int)pk;
  }
}

// ---------------- Kernel 3: fused grouped GEMM + gated combine ----------------
// 256 threads (4 waves = 1 wave/SIMD -> 512-reg budget; a 512-thr block
// forces 2 waves/SIMD and a 128-arch-VGPR split -> R6-R9's GB-scale spills).
// Block tile 256x128, per-wave 128x64 (8x4 frags of 16x16x128 MX-fp8).
// Grid 256 = 1 block/CU. R5's proven shell: e-outer linear steps s=e*16+kt,
// A/B dbuf LDS via global_load_lds, both-sides XOR swizzle, counted
// vmcnt(12), 2 barriers/step. acc[8][4] is mfma C-CHAINED (AGPR, zero VALU
// per step); gate folded once per expert boundary into outacc[8][4] (AGPR).
// Arch-VGPR demand ~80-100: bv 32 + av 8 + addresses. LDS/step/CU: 96KB
// reads vs 1049 cyc MFMA -> balanced (R5's 64x64 waves were 2x worse).
__global__ __launch_bounds__(256, 1) void k_moe_gemm(
    const unsigned char* __restrict__ x8,   // [M, D]
    const unsigned char* __restrict__ w8,   // [E, H, D]
    const float* __restrict__ gate,         // [M, 8]
    float* __restrict__ out)                // [M, H] f32
{
  extern __shared__ unsigned char smem[];   // 2*32768 A + 2*16384 B + 8192 G

  const int tid  = threadIdx.x;
  const int lane = tid & 63;
  const int wid  = tid >> 6;        // 0..3
  const int wm   = wid >> 1;        // 0..1  (128-row group)
  const int wn   = wid & 1;         // 0..1  (64-col group)

  // XCD chunking: 256 blocks; each XCD owns a 4x8 square of (m,h) tiles.
  const int bid   = blockIdx.x;
  const int xcd   = bid & 7;
  const int local = bid >> 3;                        // 0..31
  const int tm    = (xcd >> 1) * 4 + (local >> 3);   // 0..15
  const int tn    = (xcd & 1) * 8 + (local & 7);     // 0..15
  const int bm    = tm * 256;
  const int bn    = tn * 128;

  const int lrow = lane & 15;
  const int lk   = lane >> 4;                  // 0..3 -> 32B k-block
  const int c0   = (lk * 32) ^ ((lrow & 7) << 4);
  const int c1   = c0 ^ 16;

  // staging coords: thread covers row strow of each 32-row slab,
  // inverse-swizzled col stcol (involution within the 128B row).
  const int strow = tid >> 3;                  // 0..31
  const int stcol = ((tid & 7) * 16) ^ ((strow & 7) << 4);
  const unsigned char* asrc = x8 + (size_t)(bm + strow) * DDIM + stcol;
  const unsigned char* bsrc = w8 + (size_t)(bn + strow) * DDIM + stcol;

  float* sGf = (float*)(smem + 98304);         // [8 experts][256 rows]

  // gate cache: thread tid owns row bm+tid for all 8 experts
  {
    const float4 g0 = *(const float4*)(gate + (size_t)(bm + tid) * EDIM);
    const float4 g1 = *(const float4*)(gate + (size_t)(bm + tid) * EDIM + 4);
    sGf[0 * 256 + tid] = g0.x; sGf[1 * 256 + tid] = g0.y;
    sGf[2 * 256 + tid] = g0.z; sGf[3 * 256 + tid] = g0.w;
    sGf[4 * 256 + tid] = g1.x; sGf[5 * 256 + tid] = g1.y;
    sGf[6 * 256 + tid] = g1.z; sGf[7 * 256 + tid] = g1.w;
  }

  v4f acc[8][4];      // per-expert partial, mfma C-chained (AGPR)
  v4f outacc[8][4];   // gated running sum (AGPR)
#pragma unroll
  for (int i = 0; i < 8; ++i)
#pragma unroll
    for (int j = 0; j < 4; ++j) {
      acc[i][j][0] = 0.f; acc[i][j][1] = 0.f;
      acc[i][j][2] = 0.f; acc[i][j][3] = 0.f;
      outacc[i][j][0] = 0.f; outacc[i][j][1] = 0.f;
      outacc[i][j][2] = 0.f; outacc[i][j][3] = 0.f;
    }

// stage step S (A k-tile + B tile): 8 + 4 loads/thread = vmcnt unit 12
#define STAGE(S) do {                                                          \
    const int    kb_ = ((S) & 15) * 128;                                       \
    const size_t eo_ = (size_t)((S) >> 4) * HD;                                \
    unsigned char* la_ = smem + ((S) & 1) * 32768;                             \
    unsigned char* lb_ = smem + 65536 + ((S) & 1) * 16384;                     \
    _Pragma("unroll") for (int i = 0; i < 8; ++i)                              \
      gl2lds16(asrc + (size_t)i * (32 * DDIM) + kb_,                           \
               (void*)(la_ + i * 4096 + wid * 1024));                          \
    _Pragma("unroll") for (int i = 0; i < 4; ++i)                              \
      gl2lds16(bsrc + eo_ + (size_t)i * (32 * DDIM) + kb_,                     \
               (void*)(lb_ + i * 4096 + wid * 1024));                          \
  } while (0)

#define COMP(S) do {                                                           \
    const unsigned char* pA_ = smem + ((S) & 1) * 32768 +                      \
                               (size_t)(wm * 128 + lrow) * 128;                \
    const unsigned char* pB_ = smem + 65536 + ((S) & 1) * 16384 +              \
                               (size_t)(wn * 64 + lrow) * 128;                 \
    v8i bv_[4];                                                                \
    _Pragma("unroll") for (int j = 0; j < 4; ++j) {                            \
      union { v8i v; v4i h[2]; } u_;                                           \
      u_.h[0] = *(const v4i*)(pB_ + j * 2048 + c0);                            \
      u_.h[1] = *(const v4i*)(pB_ + j * 2048 + c1);                            \
      bv_[j] = u_.v;                                                           \
    }                                                                          \
    __builtin_amdgcn_s_setprio(1);                                             \
    _Pragma("unroll") for (int i = 0; i < 8; ++i) {                            \
      union { v8i v; v4i h[2]; } ua_;                                          \
      ua_.h[0] = *(const v4i*)(pA_ + i * 2048 + c0);                           \
      ua_.h[1] = *(const v4i*)(pA_ + i * 2048 + c1);                           \
      const v8i av_ = ua_.v;                                                   \
      _Pragma("unroll") for (int j = 0; j < 4; ++j)                            \
        acc[i][j] = __builtin_amdgcn_mfma_scale_f32_16x16x128_f8f6f4(          \
            av_, bv_[j], acc[i][j], 0 /*fp8*/, 0 /*fp8*/,                      \
            0, 127 /*e8m0 1.0*/, 0, 127 /*e8m0 1.0*/);                         \
    }                                                                          \
    __builtin_amdgcn_s_setprio(0);                                             \
    if (((S) & 15) == 15) {     /* expert boundary: fold gate, reset acc */    \
      const int e_ = (S) >> 4;                                                 \
      _Pragma("unroll") for (int i = 0; i < 8; ++i) {                          \
        const v4f g4_ =                                                        \
            *(const v4f*)(sGf + e_ * 256 + wm * 128 + i * 16 + lk * 4);        \
        _Pragma("unroll") for (int j = 0; j < 4; ++j) {                        \
          outacc[i][j][0] += g4_[0] * acc[i][j][0]; acc[i][j][0] = 0.f;        \
          outacc[i][j][1] += g4_[1] * acc[i][j][1]; acc[i][j][1] = 0.f;        \
          outacc[i][j][2] += g4_[2] * acc[i][j][2]; acc[i][j][2] = 0.f;        \
          outacc[i][j][3] += g4_[3] * acc[i][j][3]; acc[i][j][3] = 0.f;        \
        }                                                                      \
      }                                                                        \
    }                                                                          \
  } while (0)

  STAGE(0);
  __syncthreads();   // drains prologue loads + publishes sGf (once)

  for (int s = 0; s < 127; ++s) {
    STAGE(s + 1);
    asm volatile("s_waitcnt vmcnt(12)" ::: "memory");
    __builtin_amdgcn_s_barrier();
    __builtin_amdgcn_sched_barrier(0);
    COMP(s);
    __builtin_amdgcn_s_barrier();
  }
  asm volatile("s_waitcnt vmcnt(0)" ::: "memory");
  __builtin_amdgcn_s_barrier();
  COMP(127);

#undef COMP
#undef STAGE

  // epilogue: direct coalesced stores (single block per output tile)
#pragma unroll
  for (int i = 0; i < 8; ++i)
#pragma unroll
    for (int q = 0; q < 4; ++q) {
      const size_t r = (size_t)(bm + wm * 128 + i * 16 + lk * 4 + q);
      float* orow = out + r * HDIM + bn + wn * 64 + lrow;
#pragma unroll
      for (int j = 0; j < 4; ++j)
        orow[j * 16] = outacc[i][j][q];
    }
}

extern "C" void kernel_launch(void* const* d_in, const int* in_sizes, int n_in,
                              void* d_out, int out_size, void* d_ws, size_t ws_size,
                              hipStream_t stream) {
  (void)in_sizes; (void)n_in; (void)out_size; (void)ws_size;
  const float* x        = (const float*)d_in[0];
  const float* gate_w   = (const float*)d_in[1];
  const float* gate_b   = (const float*)d_in[2];
  const float* expert_w = (const float*)d_in[3];
  float* out = (float*)d_out;

  char* ws = (char*)d_ws;
  float* gate       = (float*)ws;                                   // 131072 B
  unsigned char* x8 = (unsigned char*)(ws + 131072);                // 8 MiB
  unsigned char* w8 = (unsigned char*)(ws + 131072 + (size_t)MDIM * DDIM);

  hipLaunchKernelGGL(k_gate_xq, dim3(MDIM / 4), dim3(256), 0, stream,
                     x, gate_w, gate_b, gate, x8);
  hipLaunchKernelGGL(k_wq, dim3(4096), dim3(256), 0, stream, expert_w, w8);
  hipLaunchKernelGGL(k_moe_gemm, dim3(256), dim3(256), 106496, stream,
                     x8, w8, gate, out);
}

// Round 11
// 166.885 us; speedup vs baseline: 18.0334x; 1.2575x over previous
//
#include <hip/hip_runtime.h>
#include <hip/hip_bf16.h>

#define MDIM 4096
#define DDIM 2048
#define HDIM 2048
#define EDIM 8
#define HD   ((size_t)HDIM * DDIM)

typedef float v4f __attribute__((ext_vector_type(4)));
typedef int   v4i __attribute__((ext_vector_type(4)));
typedef int   v8i __attribute__((ext_vector_type(8)));

// async global->LDS, 16B per lane. lds pointer must be wave-uniform
// (HW writes base + lane*16).
__device__ __forceinline__ void gl2lds16(const void* g, void* l) {
  __builtin_amdgcn_global_load_lds(
      (const __attribute__((address_space(1))) void*)g,
      (__attribute__((address_space(3))) void*)l,
      16, 0, 0);
}

// ---------------- Kernel 1: gating softmax + fp8 quantize of x ----------------
__global__ __launch_bounds__(256) void k_gate_xq(
    const float* __restrict__ x, const float* __restrict__ gw,
    const float* __restrict__ gb, float* __restrict__ gate,
    unsigned char* __restrict__ x8)
{
  const int wid  = threadIdx.x >> 6;
  const int lane = threadIdx.x & 63;
  const int m    = blockIdx.x * 4 + wid;

  const float4* xr = (const float4*)(x + (size_t)m * DDIM);
  unsigned int* qr = (unsigned int*)(x8 + (size_t)m * DDIM);

  float part[EDIM];
#pragma unroll
  for (int e = 0; e < EDIM; ++e) part[e] = 0.f;

#pragma unroll
  for (int it = 0; it < DDIM / 4 / 64; ++it) {   // 8 iterations
    const int idx = it * 64 + lane;
    const float4 xv = xr[idx];
    int pk = __builtin_amdgcn_cvt_pk_fp8_f32(xv.x, xv.y, 0, false);
    pk = __builtin_amdgcn_cvt_pk_fp8_f32(xv.z, xv.w, pk, true);
    qr[idx] = (unsigned int)pk;
#pragma unroll
    for (int e = 0; e < EDIM; ++e) {
      const float4 wv = ((const float4*)(gw + (size_t)e * DDIM))[idx];
      part[e] += xv.x * wv.x + xv.y * wv.y + xv.z * wv.z + xv.w * wv.w;
    }
  }
#pragma unroll
  for (int e = 0; e < EDIM; ++e) {
#pragma unroll
    for (int off = 32; off > 0; off >>= 1)
      part[e] += __shfl_xor(part[e], off);
  }
  float lg[EDIM];
  float s = 0.f;
#pragma unroll
  for (int e = 0; e < EDIM; ++e) lg[e] = part[e] + gb[e];
  float mx = lg[0];
#pragma unroll
  for (int e = 1; e < EDIM; ++e) mx = fmaxf(mx, lg[e]);
#pragma unroll
  for (int e = 0; e < EDIM; ++e) { lg[e] = expf(lg[e] - mx); s += lg[e]; }
  const float inv = 1.f / s;
  if (lane < EDIM) gate[m * EDIM + lane] = lg[lane] * inv;
}

// ---------------- Kernel 2: fp8 quantize of expert_w --------------------------
__global__ void k_wq(const float* __restrict__ w, unsigned char* __restrict__ w8)
{
  const long long n4 = (long long)EDIM * HDIM * DDIM / 4;
  const long long stride = (long long)gridDim.x * blockDim.x;
  for (long long i = (long long)blockIdx.x * blockDim.x + threadIdx.x; i < n4;
       i += stride) {
    const float4 v = ((const float4*)w)[i];
    int pk = __builtin_amdgcn_cvt_pk_fp8_f32(v.x, v.y, 0, false);
    pk = __builtin_amdgcn_cvt_pk_fp8_f32(v.z, v.w, pk, true);
    ((unsigned int*)w8)[i] = (unsigned int)pk;
  }
}

// ---------------- Kernel 3: fused grouped GEMM + gated combine ----------------
// R10 shell halved for 2-blocks/CU overlap: tile 128x128, grid 512 (2/CU),
// 256 threads (4 waves 2m x 2n, 64x64 per wave). Per-wave regs: acc[4][4] +
// outacc[4][4] = 128 AGPR + ~100 arch ~= 230 total <= 256 -> 2 waves/SIMD
// (two INDEPENDENT blocks per CU: no shared barrier, one block's MFMA hides
// the other's stage/vmcnt/barrier stalls -- R10 at 1 wave/SIMD had zero TLP,
// MfmaUtil 30%). Register model (R6-R10): CSV VGPR_Count is arch-only; HW
// occupancy uses arch+AGPR total vs 512/SIMD pool; 512-thr blocks force a
// 256-total cap -> spill; 256-thr blocks with <=256 total are safe.
// e-outer linear steps s=e*16+kt, A/B dbuf global_load_lds, both-sides XOR
// swizzle, counted vmcnt(8) (8 loads/thread/stage), C-chained MFMA (AGPR),
// gate folded at expert boundaries, setprio around MFMA.
__global__ __launch_bounds__(256, 2) void k_moe_gemm(
    const unsigned char* __restrict__ x8,   // [M, D]
    const unsigned char* __restrict__ w8,   // [E, H, D]
    const float* __restrict__ gate,         // [M, 8]
    float* __restrict__ out)                // [M, H] f32
{
  extern __shared__ unsigned char smem[];   // 2*16K A + 2*16K B + 4K G = 68K

  const int tid  = threadIdx.x;
  const int lane = tid & 63;
  const int wid  = tid >> 6;        // 0..3
  const int wm   = wid >> 1;        // 0..1  (64-row group)
  const int wn   = wid & 1;         // 0..1  (64-col group)

  // XCD chunking: 512 blocks; each XCD owns an 8x8 square of (m,h) tiles.
  const int bid   = blockIdx.x;
  const int xcd   = bid & 7;
  const int local = bid >> 3;                        // 0..63
  const int tm    = (xcd >> 1) * 8 + (local >> 3);   // 0..31
  const int tn    = (xcd & 1) * 8 + (local & 7);     // 0..15
  const int bm    = tm * 128;
  const int bn    = tn * 128;

  const int lrow = lane & 15;
  const int lk   = lane >> 4;                  // 0..3 -> 32B k-block
  const int c0   = (lk * 32) ^ ((lrow & 7) << 4);
  const int c1   = c0 ^ 16;

  // staging coords: thread covers row strow of each 32-row slab,
  // inverse-swizzled col stcol (involution within the 128B row).
  const int strow = tid >> 3;                  // 0..31
  const int stcol = ((tid & 7) * 16) ^ ((strow & 7) << 4);
  const unsigned char* asrc = x8 + (size_t)(bm + strow) * DDIM + stcol;
  const unsigned char* bsrc = w8 + (size_t)(bn + strow) * DDIM + stcol;

  float* sGf = (float*)(smem + 65536);         // [8 experts][128 rows]

  // gate cache: threads 0..127 own row bm+tid for all 8 experts
  if (tid < 128) {
    const float4 g0 = *(const float4*)(gate + (size_t)(bm + tid) * EDIM);
    const float4 g1 = *(const float4*)(gate + (size_t)(bm + tid) * EDIM + 4);
    sGf[0 * 128 + tid] = g0.x; sGf[1 * 128 + tid] = g0.y;
    sGf[2 * 128 + tid] = g0.z; sGf[3 * 128 + tid] = g0.w;
    sGf[4 * 128 + tid] = g1.x; sGf[5 * 128 + tid] = g1.y;
    sGf[6 * 128 + tid] = g1.z; sGf[7 * 128 + tid] = g1.w;
  }

  v4f acc[4][4];      // per-expert partial, mfma C-chained (AGPR)
  v4f outacc[4][4];   // gated running sum (AGPR)
#pragma unroll
  for (int i = 0; i < 4; ++i)
#pragma unroll
    for (int j = 0; j < 4; ++j) {
      acc[i][j][0] = 0.f; acc[i][j][1] = 0.f;
      acc[i][j][2] = 0.f; acc[i][j][3] = 0.f;
      outacc[i][j][0] = 0.f; outacc[i][j][1] = 0.f;
      outacc[i][j][2] = 0.f; outacc[i][j][3] = 0.f;
    }

// stage step S (A k-tile + B tile): 4 + 4 loads/thread = vmcnt unit 8
#define STAGE(S) do {                                                          \
    const int    kb_ = ((S) & 15) * 128;                                       \
    const size_t eo_ = (size_t)((S) >> 4) * HD;                                \
    unsigned char* la_ = smem + ((S) & 1) * 16384;                             \
    unsigned char* lb_ = smem + 32768 + ((S) & 1) * 16384;                     \
    _Pragma("unroll") for (int i = 0; i < 4; ++i)                              \
      gl2lds16(asrc + (size_t)i * (32 * DDIM) + kb_,                           \
               (void*)(la_ + i * 4096 + wid * 1024));                          \
    _Pragma("unroll") for (int i = 0; i < 4; ++i)                              \
      gl2lds16(bsrc + eo_ + (size_t)i * (32 * DDIM) + kb_,                     \
               (void*)(lb_ + i * 4096 + wid * 1024));                          \
  } while (0)

#define COMP(S) do {                                                           \
    const unsigned char* pA_ = smem + ((S) & 1) * 16384 +                      \
                               (size_t)(wm * 64 + lrow) * 128;                 \
    const unsigned char* pB_ = smem + 32768 + ((S) & 1) * 16384 +              \
                               (size_t)(wn * 64 + lrow) * 128;                 \
    v8i bv_[4];                                                                \
    _Pragma("unroll") for (int j = 0; j < 4; ++j) {                            \
      union { v8i v; v4i h[2]; } u_;                                           \
      u_.h[0] = *(const v4i*)(pB_ + j * 2048 + c0);                            \
      u_.h[1] = *(const v4i*)(pB_ + j * 2048 + c1);                            \
      bv_[j] = u_.v;                                                           \
    }                                                                          \
    __builtin_amdgcn_s_setprio(1);                                             \
    _Pragma("unroll") for (int i = 0; i < 4; ++i) {                            \
      union { v8i v; v4i h[2]; } ua_;                                          \
      ua_.h[0] = *(const v4i*)(pA_ + i * 2048 + c0);                           \
      ua_.h[1] = *(const v4i*)(pA_ + i * 2048 + c1);                           \
      const v8i av_ = ua_.v;                                                   \
      _Pragma("unroll") for (int j = 0; j < 4; ++j)                            \
        acc[i][j] = __builtin_amdgcn_mfma_scale_f32_16x16x128_f8f6f4(          \
            av_, bv_[j], acc[i][j], 0 /*fp8*/, 0 /*fp8*/,                      \
            0, 127 /*e8m0 1.0*/, 0, 127 /*e8m0 1.0*/);                         \
    }                                                                          \
    __builtin_amdgcn_s_setprio(0);                                             \
    if (((S) & 15) == 15) {     /* expert boundary: fold gate, reset acc */    \
      const int e_ = (S) >> 4;                                                 \
      _Pragma("unroll") for (int i = 0; i < 4; ++i) {                          \
        const v4f g4_ =                                                        \
            *(const v4f*)(sGf + e_ * 128 + wm * 64 + i * 16 + lk * 4);         \
        _Pragma("unroll") for (int j = 0; j < 4; ++j) {                        \
          outacc[i][j][0] += g4_[0] * acc[i][j][0]; acc[i][j][0] = 0.f;        \
          outacc[i][j][1] += g4_[1] * acc[i][j][1]; acc[i][j][1] = 0.f;        \
          outacc[i][j][2] += g4_[2] * acc[i][j][2]; acc[i][j][2] = 0.f;        \
          outacc[i][j][3] += g4_[3] * acc[i][j][3]; acc[i][j][3] = 0.f;        \
        }                                                                      \
      }                                                                        \
    }                                                                          \
  } while (0)

  STAGE(0);
  __syncthreads();   // drains prologue loads + publishes sGf (once)

  for (int s = 0; s < 127; ++s) {
    STAGE(s + 1);
    asm volatile("s_waitcnt vmcnt(8)" ::: "memory");
    __builtin_amdgcn_s_barrier();
    __builtin_amdgcn_sched_barrier(0);
    COMP(s);
    __builtin_amdgcn_s_barrier();
  }
  asm volatile("s_waitcnt vmcnt(0)" ::: "memory");
  __builtin_amdgcn_s_barrier();
  COMP(127);

#undef COMP
#undef STAGE

  // epilogue: direct coalesced stores (single block per output tile)
#pragma unroll
  for (int i = 0; i < 4; ++i)
#pragma unroll
    for (int q = 0; q < 4; ++q) {
      const size_t r = (size_t)(bm + wm * 64 + i * 16 + lk * 4 + q);
      float* orow = out + r * HDIM + bn + wn * 64 + lrow;
#pragma unroll
      for (int j = 0; j < 4; ++j)
        orow[j * 16] = outacc[i][j][q];
    }
}

extern "C" void kernel_launch(void* const* d_in, const int* in_sizes, int n_in,
                              void* d_out, int out_size, void* d_ws, size_t ws_size,
                              hipStream_t stream) {
  (void)in_sizes; (void)n_in; (void)out_size; (void)ws_size;
  const float* x        = (const float*)d_in[0];
  const float* gate_w   = (const float*)d_in[1];
  const float* gate_b   = (const float*)d_in[2];
  const float* expert_w = (const float*)d_in[3];
  float* out = (float*)d_out;

  char* ws = (char*)d_ws;
  float* gate       = (float*)ws;                                   // 131072 B
  unsigned char* x8 = (unsigned char*)(ws + 131072);                // 8 MiB
  unsigned char* w8 = (unsigned char*)(ws + 131072 + (size_t)MDIM * DDIM);

  hipLaunchKernelGGL(k_gate_xq, dim3(MDIM / 4), dim3(256), 0, stream,
                     x, gate_w, gate_b, gate, x8);
  hipLaunchKernelGGL(k_wq, dim3(4096), dim3(256), 0, stream, expert_w, w8);
  hipLaunchKernelGGL(k_moe_gemm, dim3(512), dim3(256), 69632, stream,
                     x8, w8, gate, out);
}